// Round 5
// baseline (218.930 us; speedup 1.0000x reference)
//
#include <hip/hip_runtime.h>
#include <stdint.h>
#include <stddef.h>

// DynamicRouter: logits = x @ W^T / T; top-2; softmax; scatter.
// B=8192, D=4096, E=64, K=2.
// R5: split-K. K1 (gemm_partial): 64 rowgroups x 8 K-slices, 8 m-tile waves
// per block, NO LDS / NO barriers in K-loop, x+w register double-buffered at
// distance 2, w slice per block = 128 KB (w L2 traffic 512->64 MB, L1-shared
// across the 8 waves). Partials to ws. K2 (reduce_top2): deterministic
// ascending-ks reduce + butterfly top-2 + softmax + scatter.

typedef __attribute__((ext_vector_type(8))) short short8;   // 8 bf16 (4 VGPRs)
typedef __attribute__((ext_vector_type(4))) float f32x4;    // MFMA accumulator

static constexpr int kB = 8192;
static constexpr int kD = 4096;
static constexpr int kE = 64;
static constexpr int kSteps = kD / 32;      // 128 global K-steps of 32
static constexpr int kKS = 8;               // K-slices (split-K factor)
static constexpr int kSPS = kSteps / kKS;   // 16 steps per slice
static constexpr int kRG = 64;              // row-groups
static constexpr int kRPB = kB / kRG;       // 128 rows per block

__device__ __forceinline__ uint32_t bf16_rne(float v) {
    uint32_t u = __builtin_bit_cast(uint32_t, v);
    return (u + 0x7FFFu + ((u >> 16) & 1u)) >> 16;
}

// fp32x8 -> bf16 hi/lo split (hi RNE; lo = RNE(exact residual))
__device__ __forceinline__ void cvt8(const f32x4& a0, const f32x4& a1,
                                     short8& ah, short8& al) {
#pragma unroll
    for (int j = 0; j < 4; ++j) {
        float xv = a0[j];
        uint32_t u  = __builtin_bit_cast(uint32_t, xv);
        uint32_t rh = (u + 0x7FFFu + ((u >> 16) & 1u)) & 0xFFFF0000u;
        ah[j] = (short)(rh >> 16);
        al[j] = (short)bf16_rne(xv - __builtin_bit_cast(float, rh));
        float yv = a1[j];
        uint32_t u2  = __builtin_bit_cast(uint32_t, yv);
        uint32_t rh2 = (u2 + 0x7FFFu + ((u2 >> 16) & 1u)) & 0xFFFF0000u;
        ah[j + 4] = (short)(rh2 >> 16);
        al[j + 4] = (short)bf16_rne(yv - __builtin_bit_cast(float, rh2));
    }
}

// Split gate_w fp32 -> bf16 hi/lo in MFMA-B-fragment-swizzled layout:
// chunk index ((ntile*128 + s)*64 + lane) holds, for lane l:
//   w[e = ntile*16 + (l&15)][k = s*32 + (l>>4)*8 + j], j=0..7  (16 B contiguous)
__global__ __launch_bounds__(256) void prep_w_kernel(
    const float* __restrict__ w, short* __restrict__ w_hi, short* __restrict__ w_lo)
{
    int tid  = blockIdx.x * 256 + threadIdx.x;   // 0..32767
    int lane = tid & 63;
    int s    = (tid >> 6) & (kSteps - 1);
    int nt   = tid >> 13;                        // 0..3
    int e = nt * 16 + (lane & 15);
    int k = s * 32 + (lane >> 4) * 8;
    const float* src = w + (size_t)e * kD + k;
    short8 hi, lo;
#pragma unroll
    for (int j = 0; j < 8; ++j) {
        float xv = src[j];
        uint32_t u  = __builtin_bit_cast(uint32_t, xv);
        uint32_t rh = (u + 0x7FFFu + ((u >> 16) & 1u)) & 0xFFFF0000u;
        hi[j] = (short)(rh >> 16);
        float lf = xv - __builtin_bit_cast(float, rh);   // exact residual
        lo[j] = (short)bf16_rne(lf);
    }
    ((short8*)w_hi)[tid] = hi;
    ((short8*)w_lo)[tid] = lo;
}

// K1: block = (rowgroup rg, K-slice ks). 8 waves = 8 m-tiles of 16 rows.
// Wave computes 16 steps x 4 nt x 4 terms; acc -> partial logits in ws.
// No LDS, no barriers; x and w double-buffered in registers at distance 2.
__global__ __launch_bounds__(512, 4) void gemm_partial(
    const float* __restrict__ x, const short8* __restrict__ w_hi,
    const short8* __restrict__ w_lo, float* __restrict__ part)
{
    const int lane = threadIdx.x & 63;
    const int mt   = threadIdx.x >> 6;   // m-tile 0..7
    const int quad = lane >> 4;
    const int mr   = lane & 15;
    const int ks   = blockIdx.x >> 6;    // K-slice 0..7
    const int rg   = blockIdx.x & 63;    // row-group 0..63

    const int row0 = rg * kRPB + mt * 16;
    // A frag: lane holds x[row0+mr][ks*512 + s*32 + quad*8 .. +8)
    const float* xp = x + (size_t)(row0 + mr) * kD + ks * (kSPS * 32) + quad * 8;

    f32x4 acc[4];
#pragma unroll
    for (int nt = 0; nt < 4; ++nt) acc[nt] = (f32x4){0.f, 0.f, 0.f, 0.f};

    f32x4  xb[2][2];
    short8 wbh[2][4], wbl[2][4];

    // Prologue: load steps 0 and 1 into slots 0,1.
#pragma unroll
    for (int s = 0; s < 2; ++s) {
        const f32x4* ap = (const f32x4*)(xp + s * 32);
        xb[s][0] = ap[0];
        xb[s][1] = ap[1];
        const size_t S = (size_t)(ks * kSPS + s);
#pragma unroll
        for (int nt = 0; nt < 4; ++nt) {
            wbh[s][nt] = w_hi[(size_t)(nt * kSteps) * 64 + S * 64 + lane];
            wbl[s][nt] = w_lo[(size_t)(nt * kSteps) * 64 + S * 64 + lane];
        }
    }

#pragma unroll
    for (int s = 0; s < kSPS; ++s) {
        const int slot = s & 1;
        short8 ah, al;
        cvt8(xb[slot][0], xb[slot][1], ah, al);
#pragma unroll
        for (int nt = 0; nt < 4; ++nt) {
            // smallest terms first (same order as passing R1-R4 kernels)
            acc[nt] = __builtin_amdgcn_mfma_f32_16x16x32_bf16(al, wbl[slot][nt], acc[nt], 0, 0, 0);
            acc[nt] = __builtin_amdgcn_mfma_f32_16x16x32_bf16(al, wbh[slot][nt], acc[nt], 0, 0, 0);
            acc[nt] = __builtin_amdgcn_mfma_f32_16x16x32_bf16(ah, wbl[slot][nt], acc[nt], 0, 0, 0);
            acc[nt] = __builtin_amdgcn_mfma_f32_16x16x32_bf16(ah, wbh[slot][nt], acc[nt], 0, 0, 0);
        }
        if (s + 2 < kSPS) {   // refill this slot for step s+2 (WAR after use)
            const f32x4* ap = (const f32x4*)(xp + (s + 2) * 32);
            xb[slot][0] = ap[0];
            xb[slot][1] = ap[1];
            const size_t S = (size_t)(ks * kSPS + s + 2);
#pragma unroll
            for (int nt = 0; nt < 4; ++nt) {
                wbh[slot][nt] = w_hi[(size_t)(nt * kSteps) * 64 + S * 64 + lane];
                wbl[slot][nt] = w_lo[(size_t)(nt * kSteps) * 64 + S * 64 + lane];
            }
        }
    }

    // Store partials: part[ks][row][e]. C layout (m89-verified):
    // row_in_tile = quad*4 + reg, col = mr (within nt tile).
    float* pp = part + ((size_t)ks * kB + row0) * kE;
#pragma unroll
    for (int nt = 0; nt < 4; ++nt)
#pragma unroll
        for (int r = 0; r < 4; ++r)
            pp[(size_t)(quad * 4 + r) * kE + nt * 16 + mr] = acc[nt][r];
}

// K2: deterministic reduce over ks (ascending) + top-2 + softmax + scatter.
// Block = 256 thr = 4 waves; wave handles 4 rows; grid 512.
__global__ __launch_bounds__(256) void reduce_top2(
    const float* __restrict__ part, const float* __restrict__ temp,
    float* __restrict__ out_mat, float* __restrict__ out_idx)
{
    const int lane = threadIdx.x & 63;
    const int wv   = threadIdx.x >> 6;   // 0..3
    const float invT = 1.0f / temp[0];

#pragma unroll
    for (int i = 0; i < 4; ++i) {
        const int row = blockIdx.x * 16 + wv * 4 + i;
        float v = 0.f;
#pragma unroll
        for (int ks = 0; ks < kKS; ++ks)
            v += part[((size_t)ks * kB + row) * kE + lane];

        // Wave-wide top-2 butterfly; tie-break = lowest index (jax top_k).
        float v1 = v; int i1 = lane;
#pragma unroll
        for (int m = 1; m < 64; m <<= 1) {
            float ov = __shfl_xor(v1, m, 64);
            int   oi = __shfl_xor(i1, m, 64);
            if (ov > v1 || (ov == v1 && oi < i1)) { v1 = ov; i1 = oi; }
        }
        float vm = (lane == i1) ? -3.0e38f : v;
        float v2 = vm; int i2 = lane;
#pragma unroll
        for (int m = 1; m < 64; m <<= 1) {
            float ov = __shfl_xor(v2, m, 64);
            int   oi = __shfl_xor(i2, m, 64);
            if (ov > v2 || (ov == v2 && oi < i2)) { v2 = ov; i2 = oi; }
        }

        float e  = expf((v2 - v1) * invT);   // max-subtracted softmax
        float sm = 1.0f + e;
        out_mat[(size_t)row * kE + lane] =
            (lane == i1) ? (1.0f / sm) : ((lane == i2) ? (e / sm) : 0.0f);
        if (lane == 0)
            ((float2*)out_idx)[row] = make_float2((float)i1, (float)i2);
    }
}

extern "C" void kernel_launch(void* const* d_in, const int* in_sizes, int n_in,
                              void* d_out, int out_size, void* d_ws, size_t ws_size,
                              hipStream_t stream) {
    const float* x    = (const float*)d_in[0];
    const float* gw   = (const float*)d_in[1];
    const float* temp = (const float*)d_in[2];

    float* out_mat = (float*)d_out;                      // [8192,64] fp32
    float* out_idx = (float*)d_out + (size_t)kB * kE;    // [8192,2] idx as float

    short* w_hi = (short*)d_ws;                          // 512 KB
    short* w_lo = w_hi + (size_t)kE * kD;                // 512 KB
    float* part = (float*)(w_lo + (size_t)kE * kD);      // 8 x 8192 x 64 fp32 = 16 MB

    prep_w_kernel<<<128, 256, 0, stream>>>(gw, w_hi, w_lo);

    gemm_partial<<<kRG * kKS, 512, 0, stream>>>(
        x, (const short8*)w_hi, (const short8*)w_lo, part);

    reduce_top2<<<512, 256, 0, stream>>>(part, temp, out_mat, out_idx);
}

// Round 6
// 217.456 us; speedup vs baseline: 1.0068x; 1.0068x over previous
//
#include <hip/hip_runtime.h>
#include <stdint.h>
#include <stddef.h>

// DynamicRouter: logits = x @ W^T / T; top-2; softmax; scatter.
// B=8192, D=4096, E=64, K=2.
// R6: per-wave async pipeline. Block = 16-row m-tile, 8 waves = 8 K-slices
// (16 steps each). Each wave stages its OWN x rows via global_load_lds into a
// private 4-slot LDS ring (coalesced: 8 rows x 128 B per instruction,
// XOR-chunk-swizzled for bank-uniform ds_read_b128). NO __syncthreads in the
// K-loop; one inline-asm s_waitcnt vmcnt(10) per step keeps slot s+2 + w(s+1)
// in flight while draining slot s. w-frags register-prefetched (compiler
// tracks those deps). Partials -> ws; reduce_top2 (validated) fuses top-2 +
// softmax + scatter.

typedef __attribute__((ext_vector_type(8))) short short8;   // 8 bf16 (4 VGPRs)
typedef __attribute__((ext_vector_type(4))) float f32x4;    // MFMA accumulator

static constexpr int kB = 8192;
static constexpr int kD = 4096;
static constexpr int kE = 64;
static constexpr int kSteps = kD / 32;      // 128 global K-steps of 32
static constexpr int kKS = 8;               // K-slices = waves per block
static constexpr int kSPS = kSteps / kKS;   // 16 steps per slice
static constexpr int kMT = kB / 16;         // 512 m-tiles = grid

__device__ __forceinline__ uint32_t bf16_rne(float v) {
    uint32_t u = __builtin_bit_cast(uint32_t, v);
    return (u + 0x7FFFu + ((u >> 16) & 1u)) >> 16;
}

// fp32x8 -> bf16 hi/lo split (hi RNE; lo = RNE(exact residual))
__device__ __forceinline__ void cvt8(const f32x4& a0, const f32x4& a1,
                                     short8& ah, short8& al) {
#pragma unroll
    for (int j = 0; j < 4; ++j) {
        float xv = a0[j];
        uint32_t u  = __builtin_bit_cast(uint32_t, xv);
        uint32_t rh = (u + 0x7FFFu + ((u >> 16) & 1u)) & 0xFFFF0000u;
        ah[j] = (short)(rh >> 16);
        al[j] = (short)bf16_rne(xv - __builtin_bit_cast(float, rh));
        float yv = a1[j];
        uint32_t u2  = __builtin_bit_cast(uint32_t, yv);
        uint32_t rh2 = (u2 + 0x7FFFu + ((u2 >> 16) & 1u)) & 0xFFFF0000u;
        ah[j + 4] = (short)(rh2 >> 16);
        al[j + 4] = (short)bf16_rne(yv - __builtin_bit_cast(float, rh2));
    }
}

// async 16B global->LDS; LDS dest = wave-uniform base + lane*16 (HW rule).
__device__ __forceinline__ void glds16(const float* g, float* l) {
    __builtin_amdgcn_global_load_lds(
        (const __attribute__((address_space(1))) unsigned int*)g,
        (__attribute__((address_space(3))) unsigned int*)l, 16, 0, 0);
}

// Split gate_w fp32 -> bf16 hi/lo in MFMA-B-fragment-swizzled layout:
// chunk index ((ntile*128 + s)*64 + lane) holds, for lane l:
//   w[e = ntile*16 + (l&15)][k = s*32 + (l>>4)*8 + j], j=0..7  (16 B contiguous)
__global__ __launch_bounds__(256) void prep_w_kernel(
    const float* __restrict__ w, short* __restrict__ w_hi, short* __restrict__ w_lo)
{
    int tid  = blockIdx.x * 256 + threadIdx.x;   // 0..32767
    int lane = tid & 63;
    int s    = (tid >> 6) & (kSteps - 1);
    int nt   = tid >> 13;                        // 0..3
    int e = nt * 16 + (lane & 15);
    int k = s * 32 + (lane >> 4) * 8;
    const float* src = w + (size_t)e * kD + k;
    short8 hi, lo;
#pragma unroll
    for (int j = 0; j < 8; ++j) {
        float xv = src[j];
        uint32_t u  = __builtin_bit_cast(uint32_t, xv);
        uint32_t rh = (u + 0x7FFFu + ((u >> 16) & 1u)) & 0xFFFF0000u;
        hi[j] = (short)(rh >> 16);
        float lf = xv - __builtin_bit_cast(float, rh);   // exact residual
        lo[j] = (short)bf16_rne(lf);
    }
    ((short8*)w_hi)[tid] = hi;
    ((short8*)w_lo)[tid] = lo;
}

// K1: block = m-tile (16 rows); wave wv = K-slice wv (16 steps of 32).
// Per step, wave needs x[16 rows][32 floats] = 2 KB, staged by 2 glds16
// (8 rows x 128 B each, perfectly coalesced). LDS ring: 4 slots x 2 KB
// per wave = 64 KB/block. XOR swizzle: LDS pos p of row m holds chunk
// p ^ (m&7)  (chunk = 16 B), making ds_read_b128 bank-uniform.
__global__ __launch_bounds__(512, 4) void gemm_partial(
    const float* __restrict__ x, const short8* __restrict__ w_hi,
    const short8* __restrict__ w_lo, float* __restrict__ part)
{
    const int lane = threadIdx.x & 63;
    const int wv   = threadIdx.x >> 6;   // K-slice 0..7
    const int quad = lane >> 4;
    const int mr   = lane & 15;
    const int row0 = blockIdx.x * 16;

    __shared__ __align__(16) float smem[kKS * 4 * 512];   // 64 KB: [wave][slot][512 fl]
    float* ring = &smem[wv * 4 * 512];

    // glds source address for this lane: row 8g+(l>>3), chunk (l&7)^(l>>3).
    const int gr  = lane >> 3;           // row within 8-row group
    const int gc  = (lane & 7) ^ gr;     // XOR-swizzled chunk index
    // byte-level: x[(row0 + 8g + gr)][ks*512 + s*32 + gc*4 ..]
    const float* gbase0 = x + (size_t)(row0 + gr) * kD + wv * (kSPS * 32) + gc * 4;
    const float* gbase1 = gbase0 + (size_t)8 * kD;   // rows 8..15 group

    // ds_read addresses (floats): slot + m*32 + pos*4, pos = (2q+i)^(m&7)
    const int p0 = ((2 * quad) ^ (mr & 7)) * 4 + mr * 32;
    const int p1 = ((2 * quad + 1) ^ (mr & 7)) * 4 + mr * 32;

    f32x4 acc[4];
#pragma unroll
    for (int nt = 0; nt < 4; ++nt) acc[nt] = (f32x4){0.f, 0.f, 0.f, 0.f};

    short8 wbh[2][4], wbl[2][4];

    // Prologue: glds steps 0,1 into slots 0,1; w-frags for step 0.
#pragma unroll
    for (int s = 0; s < 2; ++s) {
        glds16(gbase0 + s * 32, ring + s * 512);
        glds16(gbase1 + s * 32, ring + s * 512 + 256);
    }
    {
        const size_t S = (size_t)(wv * kSPS);
#pragma unroll
        for (int nt = 0; nt < 4; ++nt) {
            wbh[0][nt] = w_hi[(size_t)(nt * kSteps + S) * 64 + lane];
            wbl[0][nt] = w_lo[(size_t)(nt * kSteps + S) * 64 + lane];
        }
    }

#pragma unroll
    for (int s = 0; s < kSPS; ++s) {
        const int slot = s & 3;
        const int wsl  = s & 1;
        // (1) issue glds for step s+2 into slot (s+2)&3
        if (s + 2 < kSPS) {
            const int sl2 = (s + 2) & 3;
            glds16(gbase0 + (s + 2) * 32, ring + sl2 * 512);
            glds16(gbase1 + (s + 2) * 32, ring + sl2 * 512 + 256);
        }
        // (2) issue w-frag loads for step s+1
        if (s + 1 < kSPS) {
            const size_t S = (size_t)(wv * kSPS + s + 1);
#pragma unroll
            for (int nt = 0; nt < 4; ++nt) {
                wbh[wsl ^ 1][nt] = w_hi[(size_t)(nt * kSteps + S) * 64 + lane];
                wbl[wsl ^ 1][nt] = w_lo[(size_t)(nt * kSteps + S) * 64 + lane];
            }
        }
        // (3) drain everything older than this iteration's 10 issues:
        //     guarantees slot s's glds complete; keeps slot s+2 + w(s+1) in flight.
        asm volatile("s_waitcnt vmcnt(10)" ::: "memory");

        // (4) A-frag from LDS (bank-uniform b128 reads), convert, MFMA.
        f32x4 a0 = *(const f32x4*)(ring + slot * 512 + p0);
        f32x4 a1 = *(const f32x4*)(ring + slot * 512 + p1);
        short8 ah, al;
        cvt8(a0, a1, ah, al);
#pragma unroll
        for (int nt = 0; nt < 4; ++nt) {
            // smallest terms first (same order as passing R1-R5 kernels)
            acc[nt] = __builtin_amdgcn_mfma_f32_16x16x32_bf16(al, wbl[wsl][nt], acc[nt], 0, 0, 0);
            acc[nt] = __builtin_amdgcn_mfma_f32_16x16x32_bf16(al, wbh[wsl][nt], acc[nt], 0, 0, 0);
            acc[nt] = __builtin_amdgcn_mfma_f32_16x16x32_bf16(ah, wbl[wsl][nt], acc[nt], 0, 0, 0);
            acc[nt] = __builtin_amdgcn_mfma_f32_16x16x32_bf16(ah, wbh[wsl][nt], acc[nt], 0, 0, 0);
        }
    }

    // Store partials: part[ks][row][e]. C layout (m89-verified):
    // row_in_tile = quad*4 + reg, col = mr (within nt tile).
    float* pp = part + ((size_t)wv * kB + row0) * kE;
#pragma unroll
    for (int nt = 0; nt < 4; ++nt)
#pragma unroll
        for (int r = 0; r < 4; ++r)
            pp[(size_t)(quad * 4 + r) * kE + nt * 16 + mr] = acc[nt][r];
}

// K2: deterministic reduce over ks (ascending) + top-2 + softmax + scatter.
// Block = 256 thr = 4 waves; wave handles 4 rows; grid 512. (validated R5)
__global__ __launch_bounds__(256) void reduce_top2(
    const float* __restrict__ part, const float* __restrict__ temp,
    float* __restrict__ out_mat, float* __restrict__ out_idx)
{
    const int lane = threadIdx.x & 63;
    const int wv   = threadIdx.x >> 6;   // 0..3
    const float invT = 1.0f / temp[0];

#pragma unroll
    for (int i = 0; i < 4; ++i) {
        const int row = blockIdx.x * 16 + wv * 4 + i;
        float v = 0.f;
#pragma unroll
        for (int ks = 0; ks < kKS; ++ks)
            v += part[((size_t)ks * kB + row) * kE + lane];

        // Wave-wide top-2 butterfly; tie-break = lowest index (jax top_k).
        float v1 = v; int i1 = lane;
#pragma unroll
        for (int m = 1; m < 64; m <<= 1) {
            float ov = __shfl_xor(v1, m, 64);
            int   oi = __shfl_xor(i1, m, 64);
            if (ov > v1 || (ov == v1 && oi < i1)) { v1 = ov; i1 = oi; }
        }
        float vm = (lane == i1) ? -3.0e38f : v;
        float v2 = vm; int i2 = lane;
#pragma unroll
        for (int m = 1; m < 64; m <<= 1) {
            float ov = __shfl_xor(v2, m, 64);
            int   oi = __shfl_xor(i2, m, 64);
            if (ov > v2 || (ov == v2 && oi < i2)) { v2 = ov; i2 = oi; }
        }

        float e  = expf((v2 - v1) * invT);   // max-subtracted softmax
        float sm = 1.0f + e;
        out_mat[(size_t)row * kE + lane] =
            (lane == i1) ? (1.0f / sm) : ((lane == i2) ? (e / sm) : 0.0f);
        if (lane == 0)
            ((float2*)out_idx)[row] = make_float2((float)i1, (float)i2);
    }
}

extern "C" void kernel_launch(void* const* d_in, const int* in_sizes, int n_in,
                              void* d_out, int out_size, void* d_ws, size_t ws_size,
                              hipStream_t stream) {
    const float* x    = (const float*)d_in[0];
    const float* gw   = (const float*)d_in[1];
    const float* temp = (const float*)d_in[2];

    float* out_mat = (float*)d_out;                      // [8192,64] fp32
    float* out_idx = (float*)d_out + (size_t)kB * kE;    // [8192,2] idx as float

    short* w_hi = (short*)d_ws;                          // 512 KB
    short* w_lo = w_hi + (size_t)kE * kD;                // 512 KB
    float* part = (float*)(w_lo + (size_t)kE * kD);      // 8 x 8192 x 64 fp32 = 16 MB

    prep_w_kernel<<<128, 256, 0, stream>>>(gw, w_hi, w_lo);

    gemm_partial<<<kMT, 512, 0, stream>>>(
        x, (const short8*)w_hi, (const short8*)w_lo, part);

    reduce_top2<<<512, 256, 0, stream>>>(part, temp, out_mat, out_idx);
}